// Round 6
// baseline (87.011 us; speedup 1.0000x reference)
//
#include <hip/hip_runtime.h>
#include <hip/hip_bf16.h>

typedef __attribute__((ext_vector_type(8))) short s16x8;
typedef __attribute__((ext_vector_type(4))) float f32x4;
typedef __attribute__((ext_vector_type(16))) float f32x16;
typedef __attribute__((ext_vector_type(2))) unsigned int u32x2;
typedef __attribute__((ext_vector_type(4))) unsigned int u32x4;

#define MFMA16(a, b, c) __builtin_amdgcn_mfma_f32_16x16x32_bf16((a), (b), (c), 0, 0, 0)
#define MFMA32(a, b, c) __builtin_amdgcn_mfma_f32_32x32x16_bf16((a), (b), (c), 0, 0, 0)
#define LOG2E 1.4426950408889634f

static __device__ __forceinline__ unsigned int pk2(float a, float b) {
  union { __hip_bfloat162 h2; unsigned int u; } cv;
  cv.h2 = __float22bfloat162_rn(make_float2(a, b));
  return cv.u;
}
static __device__ __forceinline__ int div7(int x) { return (x * 9363) >> 16; }  // exact 0..62
static __device__ __forceinline__ int swz256(int row, int byteoff) {
  return row * 256 + (byteoff ^ ((row & 7) << 4));
}
static __device__ __forceinline__ int swz128(int row, int byteoff) {
  return row * 128 + (byteoff ^ ((row & 7) << 4));
}

// ---------- prep: weights fp32->bf16 ; rpbm[case][head][64][64] = (rpb + mask)*log2e ----------
__global__ void swin_prep(const float* __restrict__ wq, const float* __restrict__ wk,
                          const float* __restrict__ wv, const float* __restrict__ wp,
                          const float* __restrict__ rpb_table,
                          unsigned short* __restrict__ wsW, float* __restrict__ rpbm) {
  int idx = blockIdx.x * 256 + threadIdx.x;
  if (idx < 65536) {
    int t = idx >> 14, loc = idx & 16383;
    const float* s = (t == 0) ? wq : (t == 1) ? wk : (t == 2) ? wv : wp;
    union { __hip_bfloat16 h; unsigned short u; } cv;
    cv.h = __float2bfloat16(s[loc]);
    wsW[idx] = cv.u;
  } else {
    int k = idx - 65536;               // [case(2b)][head(2b)][i(6b)][j(6b)]
    int c = k >> 14;
    int h = (k >> 12) & 3;
    int i = (k >> 6) & 63, j = k & 63;
    float val;
    if (j >= 49) val = -1e30f;
    else if (i >= 49) val = 0.f;
    else {
      int yi = div7(i), xi = i - yi * 7;
      int yj = div7(j), xj = j - yj * 7;
      int ridx = (yi - yj + 6) * 13 + (xi - xj + 6);
      val = rpb_table[ridx * 4 + h];
      int cwi = c >> 1, cwj = c & 1;
      int rgi = (cwi ? (yi < 4 ? 3 : 6) : 0) + (cwj ? (xi < 4 ? 1 : 2) : 0);
      int rgj = (cwi ? (yj < 4 ? 3 : 6) : 0) + (cwj ? (xj < 4 ? 1 : 2) : 0);
      if (rgi != rgj) val -= 100.f;
      val *= LOG2E;
    }
    rpbm[k] = val;
  }
}

// ---------- main: one 512-thread WG per (batch, window); 48 KB LDS -> 3 WG/CU ----------
__global__ __launch_bounds__(512, 6) void swin_main(
    const float* __restrict__ xq, const float* __restrict__ xk, const float* __restrict__ xv,
    const float* __restrict__ bq, const float* __restrict__ bk, const float* __restrict__ bv,
    const float* __restrict__ bp, const unsigned short* __restrict__ wsW,
    const float* __restrict__ rpbm, float* __restrict__ out) {
  // Regions: A [0,16K): X(q,k,v in turn) ; B [16K,32K): Q then V^T ; C [32K,48K): K then O
  __shared__ __align__(16) char sm[49152];

  const int tid = threadIdx.x;
  const int lane = tid & 63;
  const int wv_ = tid >> 6;       // wave 0..7
  const int l15 = lane & 15;
  const int lg = lane >> 4;       // 0..3  (16x16 path)
  const int kgrp = lg * 8;
  const int rsub = lg * 4;
  const int l31 = lane & 31;      // 32x32 path
  const int hi = lane >> 5;       // 0..1

  const int bid = blockIdx.x;
  const int b = bid >> 6;
  const int widx = bid & 63;
  const int wi = widx >> 3, wj = widx & 7;
  const long obase = (long)b * 56 * 56 * 128;
  const int mcase = ((wi == 7) ? 2 : 0) + ((wj == 7) ? 1 : 0);

  // ---- X loader: thread owns (row = tid>>3, 16 ch) ----
  const int xrow = tid >> 3;
  const int xk16 = (tid & 7) << 4;
  long xoff = -1;
  if (xrow < 49) {
    int ty = div7(xrow), tx = xrow - ty * 7;
    int ih = wi * 7 + ty + 3; if (ih >= 56) ih -= 56;
    int iw = wj * 7 + tx + 3; if (iw >= 56) iw -= 56;
    xoff = obase + (long)((ih * 56 + iw) * 128 + xk16);
  }
  float xr[16];
#pragma unroll
  for (int i = 0; i < 16; ++i) xr[i] = 0.f;

  auto issue_x = [&](const float* src) {
    if (xoff >= 0) {
      const float* p = src + xoff;
#pragma unroll
      for (int q = 0; q < 4; ++q) {
        f32x4 v = *(const f32x4*)(p + q * 4);
        xr[q * 4 + 0] = v[0]; xr[q * 4 + 1] = v[1];
        xr[q * 4 + 2] = v[2]; xr[q * 4 + 3] = v[3];
      }
    }
  };
  auto write_x = [&]() {
    unsigned int w[8];
#pragma unroll
    for (int i = 0; i < 8; ++i) w[i] = pk2(xr[2 * i], xr[2 * i + 1]);
    u32x4 a = {w[0], w[1], w[2], w[3]};
    u32x4 bb = {w[4], w[5], w[6], w[7]};
    *(u32x4*)(sm + swz256(xrow, xk16 * 2)) = a;
    *(u32x4*)(sm + swz256(xrow, xk16 * 2 + 16)) = bb;
  };

  // ---- linearT: D[n][tok] = mfma16(A=W, B=X) -> row-major [tok][ch] via b64 writes ----
  auto linearT = [&](int woff, const float* bias, float scale, int dstbase) {
    const int nrow = wv_ * 16 + l15;
    s16x8 afr[4];
#pragma unroll
    for (int kt = 0; kt < 4; ++kt)
      afr[kt] = *(const s16x8*)(wsW + woff + nrow * 128 + kt * 32 + kgrp);
    f32x4 bv4 = *(const f32x4*)(bias + wv_ * 16 + rsub);
    float bb0 = bv4[0] * scale, bb1 = bv4[1] * scale;
    float bb2 = bv4[2] * scale, bb3 = bv4[3] * scale;
#pragma unroll
    for (int tt = 0; tt < 4; ++tt) {
      f32x4 acc = {0.f, 0.f, 0.f, 0.f};
#pragma unroll
      for (int kt = 0; kt < 4; ++kt) {
        s16x8 bfr = *(const s16x8*)(sm + swz256(tt * 16 + l15, (kt * 32 + kgrp) * 2));
        acc = MFMA16(afr[kt], bfr, acc);
      }
      u32x2 pkw = {pk2(acc[0] * scale + bb0, acc[1] * scale + bb1),
                   pk2(acc[2] * scale + bb2, acc[3] * scale + bb3)};
      *(u32x2*)(sm + dstbase + swz256(tt * 16 + l15, 2 * (wv_ * 16 + rsub))) = pkw;
    }
  };

  // ---- linearV: D[tok][n] = mfma16(A=X, B=W) -> V^T [128 ch][64 tok] in B via b64 writes ----
  auto linearV = [&](int woff, const float* bias) {
    const int n = wv_ * 16 + l15;
    s16x8 bfr[4];
#pragma unroll
    for (int kt = 0; kt < 4; ++kt)
      bfr[kt] = *(const s16x8*)(wsW + woff + n * 128 + kt * 32 + kgrp);
    float bval = bias[n];
#pragma unroll
    for (int mt = 0; mt < 4; ++mt) {
      f32x4 acc = {0.f, 0.f, 0.f, 0.f};
#pragma unroll
      for (int kt = 0; kt < 4; ++kt) {
        s16x8 afr = *(const s16x8*)(sm + swz256(mt * 16 + l15, (kt * 32 + kgrp) * 2));
        acc = MFMA16(afr, bfr[kt], acc);
      }
      u32x2 pkw = {pk2(acc[0] + bval, acc[1] + bval), pk2(acc[2] + bval, acc[3] + bval)};
      *(u32x2*)(sm + 16384 + swz128(n, 2 * (mt * 16 + rsub))) = pkw;
    }
  };

  const float QSCALE = 0.17677669529663687f * LOG2E;  // 32^-0.5 * log2(e)

  issue_x(xq);
  write_x(); __syncthreads();                         // B1: Xq in A
  issue_x(xk);
  linearT(0, bq, QSCALE, 16384); __syncthreads();     // B2: Q in B
  write_x(); __syncthreads();                         // B3: Xk in A
  issue_x(xv);
  linearT(16384, bk, 1.f, 32768); __syncthreads();    // B4: K in C
  write_x();                                          // Xv -> A (visible at B5)

  // ---- QK^T (swapped, 32x32x16): S[key][q], lane = q = half*32 + l31 ----
  const int h = wv_ & 3;
  const int half = wv_ >> 2;
  const int coff = h * 32;
  unsigned int pu[2][4][2];   // packed P: pu[t][g] = keys t*32 + g*8 + 4*hi + {0..3}
  {
    s16x8 qfr[2], kfr[2][2];
#pragma unroll
    for (int s = 0; s < 2; ++s) {
      qfr[s] = *(const s16x8*)(sm + 16384 + swz256(half * 32 + l31, 2 * (coff + s * 16 + hi * 8)));
#pragma unroll
      for (int t = 0; t < 2; ++t)
        kfr[t][s] = *(const s16x8*)(sm + 32768 + swz256(t * 32 + l31, 2 * (coff + s * 16 + hi * 8)));
    }
    f32x16 S[2];
    S[0] = (f32x16)0.f; S[1] = (f32x16)0.f;
#pragma unroll
    for (int s = 0; s < 2; ++s) {
      S[0] = MFMA32(kfr[0][s], qfr[s], S[0]);
      S[1] = MFMA32(kfr[1][s], qfr[s], S[1]);
    }
    // rpb + masks (pre-baked, *log2e), fully vectorized
    const float* rpbm_h = rpbm + (((mcase << 2) + h) << 12) + (half * 32 + l31) * 64 + 4 * hi;
#pragma unroll
    for (int t = 0; t < 2; ++t)
#pragma unroll
      for (int g = 0; g < 4; ++g) {
        f32x4 rv = *(const f32x4*)(rpbm_h + t * 32 + g * 8);
#pragma unroll
        for (int e = 0; e < 4; ++e) S[t][g * 4 + e] += rv[e];
      }
    // softmax over 64 keys: 32 in-lane + partner via xor32
    float m = S[0][0];
#pragma unroll
    for (int t = 0; t < 2; ++t)
#pragma unroll
      for (int r = 0; r < 16; ++r) m = fmaxf(m, S[t][r]);
    m = fmaxf(m, __shfl_xor(m, 32));
    float sum = 0.f;
#pragma unroll
    for (int t = 0; t < 2; ++t)
#pragma unroll
      for (int r = 0; r < 16; ++r) { float e = exp2f(S[t][r] - m); S[t][r] = e; sum += e; }
    sum += __shfl_xor(sum, 32);
    float inv = 1.0f / sum;
#pragma unroll
    for (int t = 0; t < 2; ++t)
#pragma unroll
      for (int g = 0; g < 4; ++g) {
        pu[t][g][0] = pk2(S[t][g * 4 + 0] * inv, S[t][g * 4 + 1] * inv);
        pu[t][g][1] = pk2(S[t][g * 4 + 2] * inv, S[t][g * 4 + 3] * inv);
      }
  }
  __syncthreads();   // B5: Xv visible; all Q reads (B) done
  linearV(32768, bv);
  __syncthreads();   // B6: V^T in B

  // ---- PV (32x32x16): O[ch][q] = mfma32(A=V, B=P); P-frags via xor32 exchange ----
  {
    f32x16 O = (f32x16)0.f;
#pragma unroll
    for (int s = 0; s < 4; ++s) {
      const int t = s >> 1, gb = (s & 1) * 2;
      unsigned int own0 = pu[t][gb + hi][0], own1 = pu[t][gb + hi][1];
      unsigned int po0 = __shfl_xor(pu[t][gb + 1 - hi][0], 32);
      unsigned int po1 = __shfl_xor(pu[t][gb + 1 - hi][1], 32);
      union { u32x4 u; s16x8 s; } pf;
      pf.u = hi ? (u32x4){po0, po1, own0, own1} : (u32x4){own0, own1, po0, po1};
      s16x8 vfr = *(const s16x8*)(sm + 16384 + swz128(coff + l31, 2 * (s * 16 + hi * 8)));
      O = MFMA32(vfr, pf.s, O);
    }
    // O row-major [tok][ch] into C; row = half*32 + l31, 4 consecutive ch per write
#pragma unroll
    for (int g = 0; g < 4; ++g) {
      u32x2 w = {pk2(O[g * 4 + 0], O[g * 4 + 1]), pk2(O[g * 4 + 2], O[g * 4 + 3])};
      *(u32x2*)(sm + 32768 + swz256(half * 32 + l31, 2 * (coff + g * 8 + 4 * hi))) = w;
    }
  }
  __syncthreads();   // B7: O in C

  // ---- proj: D[n][tok] = mfma16(A=Wp, B=O) -> dwordx4 rolled stores ----
  {
    const int nrow = wv_ * 16 + l15;
    s16x8 afr[4];
#pragma unroll
    for (int kt = 0; kt < 4; ++kt)
      afr[kt] = *(const s16x8*)(wsW + 49152 + nrow * 128 + kt * 32 + kgrp);
    f32x4 bv4 = *(const f32x4*)(bp + wv_ * 16 + rsub);
#pragma unroll
    for (int tt = 0; tt < 4; ++tt) {
      f32x4 acc = {0.f, 0.f, 0.f, 0.f};
#pragma unroll
      for (int kt = 0; kt < 4; ++kt) {
        s16x8 bfr = *(const s16x8*)(sm + 32768 + swz256(tt * 16 + l15, (kt * 32 + kgrp) * 2));
        acc = MFMA16(afr[kt], bfr, acc);
      }
      int tok = tt * 16 + l15;
      if (tok < 49) {
        int ty = div7(tok), tx = tok - ty * 7;
        int oh = wi * 7 + ty + 3; if (oh >= 56) oh -= 56;
        int ow = wj * 7 + tx + 3; if (ow >= 56) ow -= 56;
        f32x4 res = {acc[0] + bv4[0], acc[1] + bv4[1], acc[2] + bv4[2], acc[3] + bv4[3]};
        *(f32x4*)(out + obase + (oh * 56 + ow) * 128 + wv_ * 16 + rsub) = res;
      }
    }
  }
}

extern "C" void kernel_launch(void* const* d_in, const int* in_sizes, int n_in,
                              void* d_out, int out_size, void* d_ws, size_t ws_size,
                              hipStream_t stream) {
  const float* xq = (const float*)d_in[0];
  const float* xk = (const float*)d_in[1];
  const float* xv = (const float*)d_in[2];
  const float* wq = (const float*)d_in[3];
  const float* bq = (const float*)d_in[4];
  const float* wk = (const float*)d_in[5];
  const float* bk = (const float*)d_in[6];
  const float* wv = (const float*)d_in[7];
  const float* bv = (const float*)d_in[8];
  const float* wp = (const float*)d_in[9];
  const float* bp = (const float*)d_in[10];
  const float* rpb = (const float*)d_in[11];

  unsigned short* wsW = (unsigned short*)d_ws;          // 4 x 16384 bf16 = 128 KB
  float* rpbm = (float*)((char*)d_ws + 131072);         // 4*4*64*64 f32 = 256 KB

  swin_prep<<<512, 256, 0, stream>>>(wq, wk, wv, wp, rpb, wsW, rpbm);

  float* out = (float*)d_out;
  swin_main<<<2048, 512, 0, stream>>>(xq, xk, xv, bq, bk, bv, bp, wsW, rpbm, out);
}

// Round 7
// 82.898 us; speedup vs baseline: 1.0496x; 1.0496x over previous
//
#include <hip/hip_runtime.h>
#include <hip/hip_bf16.h>

typedef __attribute__((ext_vector_type(8))) short s16x8;
typedef __attribute__((ext_vector_type(4))) float f32x4;
typedef __attribute__((ext_vector_type(16))) float f32x16;
typedef __attribute__((ext_vector_type(2))) unsigned int u32x2;
typedef __attribute__((ext_vector_type(4))) unsigned int u32x4;

#define MFMA16(a, b, c) __builtin_amdgcn_mfma_f32_16x16x32_bf16((a), (b), (c), 0, 0, 0)
#define MFMA32(a, b, c) __builtin_amdgcn_mfma_f32_32x32x16_bf16((a), (b), (c), 0, 0, 0)
#define LOG2E 1.4426950408889634f

static __device__ __forceinline__ unsigned int pk2(float a, float b) {
  union { __hip_bfloat162 h2; unsigned int u; } cv;
  cv.h2 = __float22bfloat162_rn(make_float2(a, b));
  return cv.u;
}
static __device__ __forceinline__ int div7(int x) { return (x * 9363) >> 16; }  // exact 0..62
static __device__ __forceinline__ int swz256(int row, int byteoff) {
  return row * 256 + (byteoff ^ ((row & 7) << 4));
}
static __device__ __forceinline__ int swz128(int row, int byteoff) {
  return row * 128 + (byteoff ^ ((row & 7) << 4));
}

// ---------- prep: weights fp32->bf16 ; rpbm[case][head][64][64] = (rpb + mask)*log2e ----------
__global__ void swin_prep(const float* __restrict__ wq, const float* __restrict__ wk,
                          const float* __restrict__ wv, const float* __restrict__ wp,
                          const float* __restrict__ rpb_table,
                          unsigned short* __restrict__ wsW, float* __restrict__ rpbm) {
  int idx = blockIdx.x * 256 + threadIdx.x;
  if (idx < 65536) {
    int t = idx >> 14, loc = idx & 16383;
    const float* s = (t == 0) ? wq : (t == 1) ? wk : (t == 2) ? wv : wp;
    union { __hip_bfloat16 h; unsigned short u; } cv;
    cv.h = __float2bfloat16(s[loc]);
    wsW[idx] = cv.u;
  } else {
    int k = idx - 65536;               // [case(2b)][head(2b)][i(6b)][j(6b)]
    int c = k >> 14;
    int h = (k >> 12) & 3;
    int i = (k >> 6) & 63, j = k & 63;
    float val;
    if (j >= 49) val = -1e30f;
    else if (i >= 49) val = 0.f;
    else {
      int yi = div7(i), xi = i - yi * 7;
      int yj = div7(j), xj = j - yj * 7;
      int ridx = (yi - yj + 6) * 13 + (xi - xj + 6);
      val = rpb_table[ridx * 4 + h];
      int cwi = c >> 1, cwj = c & 1;
      int rgi = (cwi ? (yi < 4 ? 3 : 6) : 0) + (cwj ? (xi < 4 ? 1 : 2) : 0);
      int rgj = (cwi ? (yj < 4 ? 3 : 6) : 0) + (cwj ? (xj < 4 ? 1 : 2) : 0);
      if (rgi != rgj) val -= 100.f;
      val *= LOG2E;
    }
    rpbm[k] = val;
  }
}

// ---------- main: one 512-thread WG per (batch, window); 48 KB LDS, 5 barriers ----------
__global__ __launch_bounds__(512, 6) void swin_main(
    const float* __restrict__ xq, const float* __restrict__ xk, const float* __restrict__ xv,
    const float* __restrict__ bq, const float* __restrict__ bk, const float* __restrict__ bv,
    const float* __restrict__ bp, const unsigned short* __restrict__ wsW,
    const float* __restrict__ rpbm, float* __restrict__ out) {
  // Regions (16 KB each): r0: Xq -> Q -> O ; r1: Xk -> K ; r2: Xv -> V^T
  __shared__ __align__(16) char sm[49152];

  const int tid = threadIdx.x;
  const int lane = tid & 63;
  const int wv_ = tid >> 6;       // wave 0..7
  const int l15 = lane & 15;
  const int lg = lane >> 4;
  const int kgrp = lg * 8;
  const int rsub = lg * 4;
  const int l31 = lane & 31;
  const int hi = lane >> 5;

  const int bid = blockIdx.x;
  const int b = bid >> 6;
  const int widx = bid & 63;
  const int wi = widx >> 3, wj = widx & 7;
  const long obase = (long)b * 56 * 56 * 128;
  const int mcase = ((wi == 7) ? 2 : 0) + ((wj == 7) ? 1 : 0);

  // ================= P0: load Xq, Xk, Xv -> LDS =================
  const int xrow = tid >> 3;           // 0..63
  const int xk16 = (tid & 7) << 4;     // ch base
  long xoff = -1;
  if (xrow < 49) {
    int ty = div7(xrow), tx = xrow - ty * 7;
    int ih = wi * 7 + ty + 3; if (ih >= 56) ih -= 56;
    int iw = wj * 7 + tx + 3; if (iw >= 56) iw -= 56;
    xoff = obase + (long)((ih * 56 + iw) * 128 + xk16);
  }
  {
    float ra[16], rb[16], rc[16];
#pragma unroll
    for (int i = 0; i < 16; ++i) { ra[i] = 0.f; rb[i] = 0.f; rc[i] = 0.f; }
    if (xoff >= 0) {
#pragma unroll
      for (int q = 0; q < 4; ++q) {
        f32x4 v = *(const f32x4*)(xq + xoff + q * 4);
        ra[q*4+0]=v[0]; ra[q*4+1]=v[1]; ra[q*4+2]=v[2]; ra[q*4+3]=v[3];
      }
#pragma unroll
      for (int q = 0; q < 4; ++q) {
        f32x4 v = *(const f32x4*)(xk + xoff + q * 4);
        rb[q*4+0]=v[0]; rb[q*4+1]=v[1]; rb[q*4+2]=v[2]; rb[q*4+3]=v[3];
      }
#pragma unroll
      for (int q = 0; q < 4; ++q) {
        f32x4 v = *(const f32x4*)(xv + xoff + q * 4);
        rc[q*4+0]=v[0]; rc[q*4+1]=v[1]; rc[q*4+2]=v[2]; rc[q*4+3]=v[3];
      }
    }
    auto wrx = [&](int base, float* r) {
      unsigned int w[8];
#pragma unroll
      for (int i = 0; i < 8; ++i) w[i] = pk2(r[2*i], r[2*i+1]);
      u32x4 a = {w[0], w[1], w[2], w[3]};
      u32x4 bb = {w[4], w[5], w[6], w[7]};
      *(u32x4*)(sm + base + swz256(xrow, xk16 * 2)) = a;
      *(u32x4*)(sm + base + swz256(xrow, xk16 * 2 + 16)) = bb;
    };
    wrx(0, ra);
    wrx(16384, rb);
    wrx(32768, rc);
  }
  __syncthreads();   // B1: Xq,Xk,Xv visible

  // ================= P1: Q,K,V projections -> packed regs =================
  const float QSCALE = 0.17677669529663687f * LOG2E;
  unsigned int qpk[4][2], kpk[4][2], vpk[4][2];
  {
    // Q: D[n][tok] = mfma16(A=Wq, B=Xq)
    const int nrow = wv_ * 16 + l15;
    {
      s16x8 afr[4];
#pragma unroll
      for (int kt = 0; kt < 4; ++kt)
        afr[kt] = *(const s16x8*)(wsW + nrow * 128 + kt * 32 + kgrp);
      f32x4 bv4 = *(const f32x4*)(bq + wv_ * 16 + rsub);
#pragma unroll
      for (int tt = 0; tt < 4; ++tt) {
        f32x4 acc = {0.f, 0.f, 0.f, 0.f};
#pragma unroll
        for (int kt = 0; kt < 4; ++kt) {
          s16x8 bfr = *(const s16x8*)(sm + swz256(tt * 16 + l15, (kt * 32 + kgrp) * 2));
          acc = MFMA16(afr[kt], bfr, acc);
        }
        qpk[tt][0] = pk2(acc[0] * QSCALE + bv4[0] * QSCALE, acc[1] * QSCALE + bv4[1] * QSCALE);
        qpk[tt][1] = pk2(acc[2] * QSCALE + bv4[2] * QSCALE, acc[3] * QSCALE + bv4[3] * QSCALE);
      }
    }
    // K
    {
      s16x8 afr[4];
#pragma unroll
      for (int kt = 0; kt < 4; ++kt)
        afr[kt] = *(const s16x8*)(wsW + 16384 + nrow * 128 + kt * 32 + kgrp);
      f32x4 bv4 = *(const f32x4*)(bk + wv_ * 16 + rsub);
#pragma unroll
      for (int tt = 0; tt < 4; ++tt) {
        f32x4 acc = {0.f, 0.f, 0.f, 0.f};
#pragma unroll
        for (int kt = 0; kt < 4; ++kt) {
          s16x8 bfr = *(const s16x8*)(sm + 16384 + swz256(tt * 16 + l15, (kt * 32 + kgrp) * 2));
          acc = MFMA16(afr[kt], bfr, acc);
        }
        kpk[tt][0] = pk2(acc[0] + bv4[0], acc[1] + bv4[1]);
        kpk[tt][1] = pk2(acc[2] + bv4[2], acc[3] + bv4[3]);
      }
    }
    // V: D[tok][n] = mfma16(A=Xv, B=Wv)  (lane = ch)
    {
      s16x8 bfrw[4];
#pragma unroll
      for (int kt = 0; kt < 4; ++kt)
        bfrw[kt] = *(const s16x8*)(wsW + 32768 + nrow * 128 + kt * 32 + kgrp);
      float bval = bv[nrow];
#pragma unroll
      for (int mt = 0; mt < 4; ++mt) {
        f32x4 acc = {0.f, 0.f, 0.f, 0.f};
#pragma unroll
        for (int kt = 0; kt < 4; ++kt) {
          s16x8 afr = *(const s16x8*)(sm + 32768 + swz256(mt * 16 + l15, (kt * 32 + kgrp) * 2));
          acc = MFMA16(afr, bfrw[kt], acc);
        }
        vpk[mt][0] = pk2(acc[0] + bval, acc[1] + bval);
        vpk[mt][1] = pk2(acc[2] + bval, acc[3] + bval);
      }
    }
  }
  __syncthreads();   // B2: all X reads done

  // ================= P2: write Q, K, V^T to LDS =================
#pragma unroll
  for (int tt = 0; tt < 4; ++tt) {
    u32x2 w = {qpk[tt][0], qpk[tt][1]};
    *(u32x2*)(sm + swz256(tt * 16 + l15, 2 * (wv_ * 16 + rsub))) = w;
  }
#pragma unroll
  for (int tt = 0; tt < 4; ++tt) {
    u32x2 w = {kpk[tt][0], kpk[tt][1]};
    *(u32x2*)(sm + 16384 + swz256(tt * 16 + l15, 2 * (wv_ * 16 + rsub))) = w;
  }
#pragma unroll
  for (int mt = 0; mt < 4; ++mt) {
    u32x2 w = {vpk[mt][0], vpk[mt][1]};
    *(u32x2*)(sm + 32768 + swz128(wv_ * 16 + l15, 2 * (mt * 16 + rsub))) = w;
  }
  __syncthreads();   // B3: Q(r0), K(r1), V^T(r2) visible

  // ================= P3: QK^T + softmax + PV (one phase) =================
  const int h = wv_ & 3;
  const int half = wv_ >> 2;
  const int coff = h * 32;
  unsigned int pu[2][4][2];
  f32x16 O;
  {
    // S initialized with rpbm (bias+mask, pre-scaled by log2e) -> MFMA C-operand
    const float* rpbm_h = rpbm + (((mcase << 2) + h) << 12) + (half * 32 + l31) * 64 + 4 * hi;
    f32x16 S[2];
#pragma unroll
    for (int t = 0; t < 2; ++t)
#pragma unroll
      for (int g = 0; g < 4; ++g) {
        f32x4 rv = *(const f32x4*)(rpbm_h + t * 32 + g * 8);
        S[t][g*4+0] = rv[0]; S[t][g*4+1] = rv[1];
        S[t][g*4+2] = rv[2]; S[t][g*4+3] = rv[3];
      }
    s16x8 qfr[2], kfr[2][2];
#pragma unroll
    for (int s = 0; s < 2; ++s) {
      qfr[s] = *(const s16x8*)(sm + swz256(half * 32 + l31, 2 * (coff + s * 16 + hi * 8)));
#pragma unroll
      for (int t = 0; t < 2; ++t)
        kfr[t][s] = *(const s16x8*)(sm + 16384 + swz256(t * 32 + l31, 2 * (coff + s * 16 + hi * 8)));
    }
#pragma unroll
    for (int s = 0; s < 2; ++s) {
      S[0] = MFMA32(kfr[0][s], qfr[s], S[0]);
      S[1] = MFMA32(kfr[1][s], qfr[s], S[1]);
    }
    // softmax over 64 keys: 32 in-lane + partner via xor32
    float m = S[0][0];
#pragma unroll
    for (int t = 0; t < 2; ++t)
#pragma unroll
      for (int r = 0; r < 16; ++r) m = fmaxf(m, S[t][r]);
    m = fmaxf(m, __shfl_xor(m, 32));
    float sum = 0.f;
#pragma unroll
    for (int t = 0; t < 2; ++t)
#pragma unroll
      for (int r = 0; r < 16; ++r) { float e = exp2f(S[t][r] - m); S[t][r] = e; sum += e; }
    sum += __shfl_xor(sum, 32);
    float inv = 1.0f / sum;
#pragma unroll
    for (int t = 0; t < 2; ++t)
#pragma unroll
      for (int g = 0; g < 4; ++g) {
        pu[t][g][0] = pk2(S[t][g*4+0] * inv, S[t][g*4+1] * inv);
        pu[t][g][1] = pk2(S[t][g*4+2] * inv, S[t][g*4+3] * inv);
      }
    // PV: O[ch][q] = mfma32(A=V, B=P); P-frags via xor32 exchange
    O = (f32x16)0.f;
#pragma unroll
    for (int s = 0; s < 4; ++s) {
      const int t = s >> 1, gb = (s & 1) * 2;
      unsigned int own0 = pu[t][gb + hi][0], own1 = pu[t][gb + hi][1];
      unsigned int po0 = __shfl_xor(pu[t][gb + 1 - hi][0], 32);
      unsigned int po1 = __shfl_xor(pu[t][gb + 1 - hi][1], 32);
      union { u32x4 u; s16x8 s; } pf;
      pf.u = hi ? (u32x4){po0, po1, own0, own1} : (u32x4){own0, own1, po0, po1};
      s16x8 vfr = *(const s16x8*)(sm + 32768 + swz128(coff + l31, 2 * (s * 16 + hi * 8)));
      O = MFMA32(vfr, pf.s, O);
    }
  }
  __syncthreads();   // B4: all Q/K reads done; r0 reusable for O

#pragma unroll
  for (int g = 0; g < 4; ++g) {
    u32x2 w = {pk2(O[g*4+0], O[g*4+1]), pk2(O[g*4+2], O[g*4+3])};
    *(u32x2*)(sm + swz256(half * 32 + l31, 2 * (coff + g * 8 + 4 * hi))) = w;
  }
  __syncthreads();   // B5: O visible in r0

  // ================= P4: proj + rolled scatter =================
  {
    const int nrow = wv_ * 16 + l15;
    s16x8 afr[4];
#pragma unroll
    for (int kt = 0; kt < 4; ++kt)
      afr[kt] = *(const s16x8*)(wsW + 49152 + nrow * 128 + kt * 32 + kgrp);
    f32x4 bv4 = *(const f32x4*)(bp + wv_ * 16 + rsub);
#pragma unroll
    for (int tt = 0; tt < 4; ++tt) {
      f32x4 acc = {0.f, 0.f, 0.f, 0.f};
#pragma unroll
      for (int kt = 0; kt < 4; ++kt) {
        s16x8 bfr = *(const s16x8*)(sm + swz256(tt * 16 + l15, (kt * 32 + kgrp) * 2));
        acc = MFMA16(afr[kt], bfr, acc);
      }
      int tok = tt * 16 + l15;
      if (tok < 49) {
        int ty = div7(tok), tx = tok - ty * 7;
        int oh = wi * 7 + ty + 3; if (oh >= 56) oh -= 56;
        int ow = wj * 7 + tx + 3; if (ow >= 56) ow -= 56;
        f32x4 res = {acc[0] + bv4[0], acc[1] + bv4[1], acc[2] + bv4[2], acc[3] + bv4[3]};
        *(f32x4*)(out + obase + (oh * 56 + ow) * 128 + wv_ * 16 + rsub) = res;
      }
    }
  }
}

extern "C" void kernel_launch(void* const* d_in, const int* in_sizes, int n_in,
                              void* d_out, int out_size, void* d_ws, size_t ws_size,
                              hipStream_t stream) {
  const float* xq = (const float*)d_in[0];
  const float* xk = (const float*)d_in[1];
  const float* xv = (const float*)d_in[2];
  const float* wq = (const float*)d_in[3];
  const float* bq = (const float*)d_in[4];
  const float* wk = (const float*)d_in[5];
  const float* bk = (const float*)d_in[6];
  const float* wv = (const float*)d_in[7];
  const float* bv = (const float*)d_in[8];
  const float* wp = (const float*)d_in[9];
  const float* bp = (const float*)d_in[10];
  const float* rpb = (const float*)d_in[11];

  unsigned short* wsW = (unsigned short*)d_ws;          // 4 x 16384 bf16 = 128 KB
  float* rpbm = (float*)((char*)d_ws + 131072);         // 4*4*64*64 f32 = 256 KB

  swin_prep<<<512, 256, 0, stream>>>(wq, wk, wv, wp, rpb, wsW, rpbm);

  float* out = (float*)d_out;
  swin_main<<<2048, 512, 0, stream>>>(xq, xk, xv, bq, bk, bv, bp, wsW, rpbm, out);
}